// Round 14
// baseline (196.529 us; speedup 1.0000x reference)
//
#include <hip/hip_runtime.h>
#include <hip/hip_bf16.h>

// QREncoder: path signature depth 4 + linear head.
// Delta architecture (R13/R14): level-4 never materialized. Δa4 = T4⊗v, so we
// store T4 [b][256][512] f32 + v + Δ(levels1-3) bf16, GEMM on increment rows
// (L4 A-fragments built in registers from T4×v), prefix-sum in the epilogue.
#define BATCH 64
#define LSEQ 256
#define CIN 7
#define CC 8
#define NSIG 4680
#define TSTEPS 255
#define ODIM 512
#define NCHUNK 16
#define CH 16
#define ROWS 256        // padded rows per batch (row 255 = zeros)
#define DCOLS 640       // Δ123 width: 72 + 512 + 56 pad
#define KPAD 4736       // 640 + 4096
#define NT123 20        // L123 K-tiles (32 wide)
#define NTILES 84       // 20 + 64 L4 tiles (64 wide)
#define WCVT_BLK 592    // 512*4736/8/512

typedef __attribute__((ext_vector_type(8))) unsigned short ushort8;
typedef __attribute__((ext_vector_type(8))) __bf16 bf16x8;
typedef __attribute__((ext_vector_type(4))) float f32x4;

__device__ __forceinline__ unsigned short f2bf(float x) {
    __hip_bfloat16 h = __float2bfloat16(x);   // RNE
    return *(unsigned short*)&h;
}

#define GLDS16(gp, lp)                                                      \
    __builtin_amdgcn_global_load_lds(                                       \
        (const __attribute__((address_space(1))) void*)(gp),                \
        (__attribute__((address_space(3))) void*)(lp), 16, 0, 0)

// ---------------------------------------------------------------------------
// prep: blocks [0,nb): a1/a2/a3-only scan, ckpt (584 f32) at t=16..240.
// blocks [nb,nb+592): W fp32 -> bf16 with column permutation [Δ123|pad|L4].
// ---------------------------------------------------------------------------
__global__ __launch_bounds__(512) void prep_kernel(const float* __restrict__ inp,
                                                   float* __restrict__ ckpt,
                                                   const float* __restrict__ W,
                                                   unsigned short* __restrict__ Wb,
                                                   int nb) {
    __shared__ float sDx[TSTEPS * CC];
    const int bx  = blockIdx.x;
    const int tid = threadIdx.x;

    if (bx < nb) {
        const int b = bx;
        const float* ip = inp + (size_t)b * LSEQ * CIN;
        for (int i = tid; i < TSTEPS * CC; i += 512) {
            int t = i >> 3, c = i & 7;
            sDx[i] = (c == 0) ? (1.0f / 255.0f)
                              : ip[(t + 1) * CIN + (c - 1)] - ip[t * CIN + (c - 1)];
        }
        __syncthreads();
        const int i1 = tid >> 6, i2 = (tid >> 3) & 7, i3 = tid & 7;
        float a1 = 0.0f, a2 = 0.0f, a3 = 0.0f;
        for (int t = 0; t < 240; ++t) {
            const float* v = &sDx[t * CC];
            const float va = v[i1], vb = v[i2], vc = v[i3];
            const float e3s = va * vb * vc * (1.0f / 6.0f);
            a3 += e3s + (a1 * vb * 0.5f + a2) * vc;
            a2 += vb * (0.5f * va + a1);
            a1 += va;
            if (((t + 1) & 15) == 0) {
                const int c = ((t + 1) >> 4) - 1;
                float* cp = ckpt + ((size_t)b * 15 + c) * 584;
                if ((tid & 63) == 0) cp[i1] = a1;
                if ((tid & 7) == 0) cp[8 + (tid >> 3)] = a2;
                cp[72 + tid] = a3;
            }
        }
    } else {
        const int vid = (bx - nb) * 512 + tid;
        if (vid < ODIM * (KPAD / 8)) {
            const int n = vid / (KPAD / 8);
            const int g = vid - n * (KPAD / 8);
            ushort8 pk;
            const float* wp = nullptr;
            if (g < 73)       wp = W + (size_t)n * NSIG + g * 8;
            else if (g >= 80) wp = W + (size_t)n * NSIG + 584 + (g - 80) * 8;
            if (wp) {
                float4 f0 = *(const float4*)wp;
                float4 f1 = *(const float4*)(wp + 4);
                pk[0] = f2bf(f0.x); pk[1] = f2bf(f0.y);
                pk[2] = f2bf(f0.z); pk[3] = f2bf(f0.w);
                pk[4] = f2bf(f1.x); pk[5] = f2bf(f1.y);
                pk[6] = f2bf(f1.z); pk[7] = f2bf(f1.w);
            } else {
#pragma unroll
                for (int e = 0; e < 8; ++e) pk[e] = 0;
            }
            *(ushort8*)(Wb + (size_t)n * KPAD + g * 8) = pk;
        }
    }
}

// ---------------------------------------------------------------------------
// delta: grid (NCHUNK, nb). Per-step increments: T4 row (512 f32), Δ123 row
// (bf16), v row (8 f32). Chunk 15 zeroes padded row 255.
// ---------------------------------------------------------------------------
__global__ __launch_bounds__(512) void delta_kernel(const float* __restrict__ inp,
                                                    const float* __restrict__ ckpt,
                                                    unsigned short* __restrict__ sigD,
                                                    float* __restrict__ T4g,
                                                    float* __restrict__ vtab) {
    __shared__ float sDx[CH * CC];
    const int chunk = blockIdx.x;
    const int b     = blockIdx.y;
    const int tid   = threadIdx.x;
    const int t0    = chunk * CH;
    const int t1    = (chunk == NCHUNK - 1) ? TSTEPS : t0 + CH;

    const float* ip = inp + (size_t)b * LSEQ * CIN;
    for (int i = tid; i < (t1 - t0) * CC; i += 512) {
        int t = t0 + (i >> 3), c = i & 7;
        sDx[i] = (c == 0) ? (1.0f / 255.0f)
                          : ip[(t + 1) * CIN + (c - 1)] - ip[t * CIN + (c - 1)];
    }
    __syncthreads();

    const int i1 = tid >> 6, i2 = (tid >> 3) & 7, i3 = tid & 7;
    float a1, a2, a3;
    if (chunk == 0) {
        a1 = a2 = a3 = 0.0f;
    } else {
        const float* cp = ckpt + ((size_t)b * 15 + (chunk - 1)) * 584;
        a1 = cp[i1];
        a2 = cp[8 + (tid >> 3)];
        a3 = cp[72 + tid];
    }

    for (int t = t0; t < t1; ++t) {
        const float* v = &sDx[(t - t0) * CC];
        const float va = v[i1], vb = v[i2], vc = v[i3];
        const float e3s = va * vb * vc * (1.0f / 6.0f);
        const float dT4 = e3s * 0.25f + a1 * vb * vc * (1.0f / 6.0f)
                        + a2 * vc * 0.5f + a3;
        const float dA3 = e3s + (a1 * vb * 0.5f + a2) * vc;
        const float dA2 = vb * (0.5f * va + a1);

        const size_t rr = (size_t)b * ROWS + t;
        T4g[rr * 512 + tid] = dT4;
        unsigned short* row = sigD + rr * DCOLS;
        row[72 + tid] = f2bf(dA3);
        if ((tid & 63) == 0) row[i1] = f2bf(va);
        if ((tid & 7) == 0) row[8 + (tid >> 3)] = f2bf(dA2);
        if (tid >= 448 && tid < 504) row[136 + tid] = 0;
        if (tid >= 504) vtab[rr * 8 + (tid - 504)] = v[tid - 504];

        a3 += dA3; a2 += dA2; a1 += va;
    }

    if (chunk == NCHUNK - 1) {
        const size_t rr = (size_t)b * ROWS + 255;
        T4g[rr * 512 + tid] = 0.0f;
        for (int c = tid; c < DCOLS; c += 512) sigD[rr * DCOLS + c] = 0;
        if (tid < 8) vtab[rr * 8 + tid] = 0.0f;
    }
}

// ---------------------------------------------------------------------------
// GEMM on increments + prefix epilogue (R14 fixes over R13):
// 1) T4s rows padded to 48B (16B-aligned): b32 frag reads 2-way-free; staged
//    via reg (float4 load at u for tile u+2, ds_write_b128 at u+1) — vmem
//    stays 3 ops/tile so vmcnt(3) counting is unchanged.
// 2) Construction pipelined: [W,t4P,bfP,t4N,bfN] then lgkm(12)->CONSTR(P)->
//    lgkm(8)->MFMA-P->lgkm(4)->CONSTR(N under MFMA-P pipe)->lgkm(0)->MFMA-N.
// 3) L123 swizzle key fixed to (lr>>1)&3 (64B row stride).
// ---------------------------------------------------------------------------
__global__ __launch_bounds__(512) void gemm_kernel(const unsigned short* __restrict__ sigD,
                                                   const float* __restrict__ T4g,
                                                   const float* __restrict__ vtab,
                                                   const unsigned short* __restrict__ Wb,
                                                   const float* __restrict__ bias,
                                                   float* __restrict__ out) {
    __shared__ unsigned short A123[3][256 * 32];   // 48 KB
    __shared__ unsigned short Bs[3][128 * 64];     // 48 KB
    __shared__ float T4s[3][256 * 12];             // 36 KB (48B/row: 8 + 4 pad)

    const int tid = threadIdx.x;
    int nt, mt;
    if (gridDim.y == 64) {
        const int li = blockIdx.y * 4 + blockIdx.x;
        const int x  = li & 7;
        const int j  = li >> 3;
        mt = x * 8 + (j >> 2);
        nt = j & 3;
    } else {
        nt = blockIdx.x; mt = blockIdx.y;
    }
    const int b    = mt;
    const int lane = tid & 63;
    const int wv   = tid >> 6;
    const int wr   = wv >> 1;
    const int wc   = wv & 1;
    const int lr   = lane & 15;
    const int lq   = lane >> 4;

    const f32x4 z4 = {0.0f, 0.0f, 0.0f, 0.0f};
    f32x4 acc[4][4];
#pragma unroll
    for (int i = 0; i < 4; ++i)
#pragma unroll
        for (int j = 0; j < 4; ++j) acc[i][j] = z4;

    float vreg[4][8];
#pragma unroll
    for (int i = 0; i < 4; ++i) {
        const float* vp = vtab + ((size_t)b * ROWS + wr * 64 + i * 16 + lr) * 8;
        float4 v0 = *(const float4*)vp;
        float4 v1 = *(const float4*)(vp + 4);
        vreg[i][0] = v0.x; vreg[i][1] = v0.y; vreg[i][2] = v0.z; vreg[i][3] = v0.w;
        vreg[i][4] = v1.x; vreg[i][5] = v1.y; vreg[i][6] = v1.z; vreg[i][7] = v1.w;
    }

    // staging geometry
    const int sr123  = tid >> 2;                            // 0..127
    const int scol32 = (((tid & 3) ^ ((sr123 >> 1) & 3)) * 8);
    const int sr64   = tid >> 3;
    const int scol64 = (((tid & 7) ^ (sr64 & 7)) * 8);
    const int rT4    = tid >> 1;                            // T4 stage row
    const int hT4    = tid & 1;                             // owner half
    const float* t4src = T4g + ((size_t)b * ROWS + rT4) * 512 + hT4 * 4;
    const int t4dst  = rT4 * 48 + hT4 * 16;                 // byte off in slot

    // fragment read geometry
    const int kel32 = (lq ^ ((lr >> 1) & 3)) * 8;           // 64B-stride key
    const int kel0  = ((lq) ^ (lr & 7)) * 8;
    const int kel1  = ((4 + lq) ^ (lr & 7)) * 8;

#define STAGE(TT)                                                           \
    do {                                                                    \
        const int tt_ = (TT);                                               \
        if (tt_ < NT123) {                                                  \
            const int bf_ = tt_ % 3;                                        \
            _Pragma("unroll")                                               \
            for (int i_ = 0; i_ < 2; ++i_)                                  \
                GLDS16(sigD + ((size_t)b * ROWS + i_ * 128 + sr123) * DCOLS \
                            + tt_ * 32 + scol32,                            \
                       (char*)A123[bf_] + i_ * 8192 + tid * 16);            \
            GLDS16(Wb + (size_t)(nt * 128 + sr123) * KPAD + tt_ * 32 + scol32, \
                   (char*)Bs[bf_] + tid * 16);                              \
        } else {                                                            \
            const int ot_ = tt_ - NT123;                                    \
            _Pragma("unroll")                                               \
            for (int i_ = 0; i_ < 2; ++i_)                                  \
                GLDS16(Wb + (size_t)(nt * 128 + i_ * 64 + sr64) * KPAD      \
                            + DCOLS + ot_ * 64 + scol64,                    \
                       (char*)Bs[tt_ % 3] + i_ * 8192 + tid * 16);          \
        }                                                                   \
    } while (0)

#define MFMA16(AF, BF)                                                      \
    do {                                                                    \
        _Pragma("unroll")                                                   \
        for (int im_ = 0; im_ < 4; ++im_)                                   \
            _Pragma("unroll")                                               \
            for (int jm_ = 0; jm_ < 4; ++jm_)                               \
                acc[im_][jm_] = __builtin_amdgcn_mfma_f32_16x16x32_bf16(    \
                    AF[im_], BF[jm_], acc[im_][jm_], 0, 0, 0);              \
    } while (0)

#define LDT4(DST, BUF, KS)                                                  \
    do {                                                                    \
        _Pragma("unroll")                                                   \
        for (int l_ = 0; l_ < 4; ++l_)                                      \
            DST[l_] = *(const float*)((const char*)T4s[BUF]                 \
                + (wr * 64 + l_ * 16 + lr) * 48 + ((KS) * 4 + lq) * 4);     \
    } while (0)

#define CONSTR(AF, T4R)                                                     \
    do {                                                                    \
        _Pragma("unroll")                                                   \
        for (int l_ = 0; l_ < 4; ++l_) {                                    \
            union { unsigned short u[8]; bf16x8 v8; } cc_;                  \
            _Pragma("unroll")                                               \
            for (int e_ = 0; e_ < 8; ++e_)                                  \
                cc_.u[e_] = f2bf(T4R[l_] * vreg[l_][e_]);                   \
            AF[l_] = cc_.v8;                                                \
        }                                                                   \
    } while (0)

// TILEBODY(U, TLD, TWR): TLD = float4 reg receiving T4 load (for tile U+2),
// TWR = float4 reg (loaded at U-1) ds_written for tile U+1's slot.
#define TILEBODY(U, TLD, TWR)                                               \
    {                                                                       \
        const int u_ = (U);                                                 \
        const int cs = u_ % 3;                                              \
        const int ws = (u_ + 1) % 3;                                        \
        if (u_ >= NT123 - 1 && u_ + 1 < NTILES)                             \
            *(float4*)((char*)T4s[ws] + t4dst) = TWR;                       \
        if (u_ < NT123) {                                                   \
            bf16x8 af[4], bfv[4];                                           \
            _Pragma("unroll")                                               \
            for (int l = 0; l < 4; ++l)                                     \
                af[l] = *(const bf16x8*)&A123[cs][(wr * 64 + l * 16 + lr) * 32 + kel32]; \
            _Pragma("unroll")                                               \
            for (int l = 0; l < 4; ++l)                                     \
                bfv[l] = *(const bf16x8*)&Bs[cs][(wc * 64 + l * 16 + lr) * 32 + kel32]; \
            if (u_ + 2 < NTILES) STAGE(u_ + 2);                             \
            if (u_ + 2 >= NT123 && u_ + 2 < NTILES)                         \
                TLD = *(const float4*)(t4src + (size_t)(u_ + 2 - NT123) * 8); \
            __builtin_amdgcn_sched_barrier(0);                              \
            asm volatile("s_waitcnt lgkmcnt(0)" ::: "memory");              \
            __builtin_amdgcn_sched_barrier(0);                              \
            __builtin_amdgcn_s_setprio(1);                                  \
            MFMA16(af, bfv);                                                \
            __builtin_amdgcn_s_setprio(0);                                  \
            __builtin_amdgcn_sched_barrier(0);                              \
        } else {                                                            \
            float t4vP[4], t4vN[4];                                         \
            bf16x8 bfP[4], bfN[4], afP[4], afN[4];                          \
            LDT4(t4vP, cs, 0);                                              \
            _Pragma("unroll")                                               \
            for (int l = 0; l < 4; ++l)                                     \
                bfP[l] = *(const bf16x8*)&Bs[cs][(wc * 64 + l * 16 + lr) * 64 + kel0]; \
            LDT4(t4vN, cs, 1);                                              \
            _Pragma("unroll")                                               \
            for (int l = 0; l < 4; ++l)                                     \
                bfN[l] = *(const bf16x8*)&Bs[cs][(wc * 64 + l * 16 + lr) * 64 + kel1]; \
            if (u_ + 2 < NTILES) {                                          \
                STAGE(u_ + 2);                                              \
                TLD = *(const float4*)(t4src + (size_t)(u_ + 2 - NT123) * 8); \
            }                                                               \
            __builtin_amdgcn_sched_barrier(0);                              \
            asm volatile("s_waitcnt lgkmcnt(12)" ::: "memory");             \
            __builtin_amdgcn_sched_barrier(0);                              \
            CONSTR(afP, t4vP);                                              \
            __builtin_amdgcn_sched_barrier(0);                              \
            asm volatile("s_waitcnt lgkmcnt(8)" ::: "memory");              \
            __builtin_amdgcn_sched_barrier(0);                              \
            __builtin_amdgcn_s_setprio(1);                                  \
            MFMA16(afP, bfP);                                               \
            __builtin_amdgcn_s_setprio(0);                                  \
            __builtin_amdgcn_sched_barrier(0);                              \
            asm volatile("s_waitcnt lgkmcnt(4)" ::: "memory");              \
            __builtin_amdgcn_sched_barrier(0);                              \
            CONSTR(afN, t4vN);                                              \
            __builtin_amdgcn_sched_barrier(0);                              \
            asm volatile("s_waitcnt lgkmcnt(0)" ::: "memory");              \
            __builtin_amdgcn_sched_barrier(0);                              \
            __builtin_amdgcn_s_setprio(1);                                  \
            MFMA16(afN, bfN);                                               \
            __builtin_amdgcn_s_setprio(0);                                  \
            __builtin_amdgcn_sched_barrier(0);                              \
        }                                                                   \
        if (u_ + 2 < NTILES) {                                              \
            asm volatile("s_waitcnt vmcnt(3)" ::: "memory");                \
            __builtin_amdgcn_sched_barrier(0);                              \
            __builtin_amdgcn_s_barrier();                                   \
            __builtin_amdgcn_sched_barrier(0);                              \
        } else if (u_ + 1 < NTILES) {                                       \
            asm volatile("s_waitcnt vmcnt(0)" ::: "memory");                \
            __builtin_amdgcn_sched_barrier(0);                              \
            __builtin_amdgcn_s_barrier();                                   \
            __builtin_amdgcn_sched_barrier(0);                              \
        }                                                                   \
    }

    // prologue: tiles 0,1 in flight (3 gloads each); wait tile 0
    STAGE(0);
    STAGE(1);
    asm volatile("s_waitcnt vmcnt(3)" ::: "memory");
    __builtin_amdgcn_sched_barrier(0);
    __builtin_amdgcn_s_barrier();
    __builtin_amdgcn_sched_barrier(0);

    float4 t4A = {0, 0, 0, 0}, t4B = {0, 0, 0, 0};
    for (int u0 = 0; u0 < NTILES; u0 += 2) {
        TILEBODY(u0,     t4A, t4B);   // even: load->t4A, write t4B
        TILEBODY(u0 + 1, t4B, t4A);   // odd:  load->t4B, write t4A
    }

    // ---- epilogue: inclusive prefix over t per output column ----
    float (*P)[32] = (float (*)[32])(&A123[0][0]);    // 32 KB region
    float* S = (float*)(&T4s[0][0]);
    const int colP = wc * 16 + lr;

    for (int jj = 0; jj < 4; ++jj) {
        __syncthreads();
#pragma unroll
        for (int i = 0; i < 4; ++i)
#pragma unroll
            for (int r = 0; r < 4; ++r)
                P[wr * 64 + i * 16 + lq * 4 + r][colP] = acc[i][jj][r];
        __syncthreads();
        if (tid < 256) {
            const int c = tid & 31, s = tid >> 5;
            float ss = 0.0f;
            for (int k = 0; k < 32; ++k) ss += P[s * 32 + k][c];
            S[s * 32 + c] = ss;
        }
        __syncthreads();
        if (tid < 32) {
            float run = 0.0f;
            for (int s = 0; s < 8; ++s) {
                float x = S[s * 32 + tid];
                S[s * 32 + tid] = run;
                run += x;
            }
        }
        __syncthreads();
        if (tid < 256) {
            const int c = tid & 31, s = tid >> 5;
            float run = S[s * 32 + c];
            for (int k = 0; k < 32; ++k) {
                run += P[s * 32 + k][c];
                P[s * 32 + k][c] = run;
            }
        }
        __syncthreads();
        for (int e = tid; e < 255 * 32; e += 512) {
            const int t = e >> 5, c = e & 31;
            const int n = nt * 128 + (c >> 4) * 64 + jj * 16 + (c & 15);
            out[((size_t)(b * 255 + t)) * ODIM + n] = P[t][c] + bias[n];
        }
    }
#undef STAGE
#undef MFMA16
#undef LDT4
#undef CONSTR
#undef TILEBODY
}

extern "C" void kernel_launch(void* const* d_in, const int* in_sizes, int n_in,
                              void* d_out, int out_size, void* d_ws, size_t ws_size,
                              hipStream_t stream) {
    const float* inp  = (const float*)d_in[0];
    const float* W    = (const float*)d_in[1];
    const float* bias = (const float*)d_in[2];
    float* out = (float*)d_out;

    const size_t wbBytes = (size_t)ODIM * KPAD * sizeof(unsigned short);
    const size_t sigPB   = (size_t)ROWS * DCOLS * sizeof(unsigned short);
    const size_t t4PB    = (size_t)ROWS * 512 * sizeof(float);
    const size_t vPB     = (size_t)ROWS * 8 * sizeof(float);
    const size_t ckptPB  = (size_t)15 * 584 * sizeof(float);
    const size_t perB    = sigPB + t4PB + vPB + ckptPB;

    int nbMax = (int)((ws_size - wbBytes) / perB);
    if (nbMax > BATCH) nbMax = BATCH;
    if (nbMax < 1) nbMax = 1;

    unsigned short* sigD = (unsigned short*)d_ws;
    float*          T4g  = (float*)((char*)d_ws + (size_t)nbMax * sigPB);
    float*          vtab = (float*)((char*)T4g + (size_t)nbMax * t4PB);
    float*          ckpt = (float*)((char*)vtab + (size_t)nbMax * vPB);
    unsigned short* Wb   = (unsigned short*)((char*)d_ws + (ws_size - wbBytes));

    for (int b0 = 0; b0 < BATCH; b0 += nbMax) {
        const int nb = (b0 + nbMax <= BATCH) ? nbMax : (BATCH - b0);
        const float* ipb = inp + (size_t)b0 * LSEQ * CIN;
        prep_kernel<<<nb + WCVT_BLK, 512, 0, stream>>>(ipb, ckpt, W, Wb, nb);
        delta_kernel<<<dim3(NCHUNK, nb), 512, 0, stream>>>(ipb, ckpt, sigD, T4g, vtab);
        gemm_kernel<<<dim3(4, nb), 512, 0, stream>>>(
            sigD, T4g, vtab, Wb, bias, out + (size_t)b0 * TSTEPS * ODIM);
    }
}

// Round 15
// 146.695 us; speedup vs baseline: 1.3397x; 1.3397x over previous
//
#include <hip/hip_runtime.h>
#include <hip/hip_bf16.h>

// Problem constants (QREncoder: path signature depth 4 + linear head)
#define BATCH 64
#define LSEQ 256
#define CIN 7
#define CC 8           // channels incl. time
#define NSIG 4680      // 8 + 64 + 512 + 4096
#define KPAD 4736      // NSIG padded to multiple of 64
#define TSTEPS 255     // LSEQ - 1
#define ODIM 512
#define NCHUNK 16      // time chunks for sig write parallelism
#define CH 16          // steps per chunk (last chunk: 15)
#define NKT 74         // KPAD / 64 K-steps
#define BM 256
#define BN 128
#define WCVT_BLK 592   // ODIM*KPAD/8/512

typedef __attribute__((ext_vector_type(8))) unsigned short ushort8;
typedef __attribute__((ext_vector_type(8))) __bf16 bf16x8;
typedef __attribute__((ext_vector_type(4))) float f32x4;

__device__ __forceinline__ unsigned short f2bf(float x) {
    __hip_bfloat16 h = __float2bfloat16(x);   // RNE
    return *(unsigned short*)&h;
}

#define GLDS16(gp, lp)                                                      \
    __builtin_amdgcn_global_load_lds(                                       \
        (const __attribute__((address_space(1))) void*)(gp),                \
        (__attribute__((address_space(3))) void*)(lp), 16, 0, 0)

// ---------------------------------------------------------------------------
// prep kernel (R11-verified): scan-checkpoint part (4 blocks/batch) + W
// conversion part (vectorized float4x2 -> ushort8) riding the same launch.
// ---------------------------------------------------------------------------
__global__ __launch_bounds__(512) void prep_kernel(const float* __restrict__ inp,
                                                   float* __restrict__ ckpt,
                                                   const float* __restrict__ W,
                                                   unsigned short* __restrict__ Wb,
                                                   int nb) {
    __shared__ float sDx[TSTEPS * CC];
    const int bx  = blockIdx.x;
    const int tid = threadIdx.x;

    if (bx < 4 * nb) {
        const int b = bx >> 2, q = bx & 3;
        const float* ip = inp + (size_t)b * LSEQ * CIN;
        for (int i = tid; i < TSTEPS * CC; i += 512) {
            int t = i >> 3, c = i & 7;
            sDx[i] = (c == 0) ? (1.0f / 255.0f)
                              : ip[(t + 1) * CIN + (c - 1)] - ip[t * CIN + (c - 1)];
        }
        __syncthreads();

        const int o  = q * 128 + (tid >> 2);
        const int e2 = tid & 3;
        const int i1 = o >> 6, i2 = (o >> 3) & 7, i3 = o & 7;
        float a1 = 0.0f, a2 = 0.0f, a3 = 0.0f, a4a = 0.0f, a4b = 0.0f;

        for (int t = 0; t < 240; ++t) {
            const float* v = &sDx[t * CC];
            const float va = v[i1], vb = v[i2], vc = v[i3];
            const float vA = v[e2], vB = v[e2 + 4];
            const float e3s = va * vb * vc * (1.0f / 6.0f);
            const float T4 = e3s * 0.25f + a1 * vb * vc * (1.0f / 6.0f)
                           + a2 * vc * 0.5f + a3;
            a4a += vA * T4;
            a4b += vB * T4;
            a3 += e3s + (a1 * vb * 0.5f + a2) * vc;
            a2 += vb * (0.5f * va + a1);
            a1 += va;

            if (((t + 1) & 15) == 0) {
                const int c = ((t + 1) >> 4) - 1;   // 0..14
                float* cp = ckpt + ((size_t)b * 15 + c) * NSIG;
                cp[584 + o * 8 + e2]     = a4a;
                cp[584 + o * 8 + e2 + 4] = a4b;
                if (e2 == 0) {
                    cp[72 + o] = a3;
                    if ((o & 7) == 0)  cp[8 + (o >> 3)] = a2;
                    if ((o & 63) == 0) cp[i1] = a1;
                }
            }
        }
    } else {
        const int vid = (bx - 4 * nb) * 512 + tid;
        if (vid < ODIM * (KPAD / 8)) {
            const int n = vid / (KPAD / 8);
            const int g = vid - n * (KPAD / 8);
            ushort8 pk;
            if (g < NSIG / 8) {
                const float* wp = W + (size_t)n * NSIG + g * 8;
                float4 f0 = *(const float4*)wp;
                float4 f1 = *(const float4*)(wp + 4);
                pk[0] = f2bf(f0.x); pk[1] = f2bf(f0.y);
                pk[2] = f2bf(f0.z); pk[3] = f2bf(f0.w);
                pk[4] = f2bf(f1.x); pk[5] = f2bf(f1.y);
                pk[6] = f2bf(f1.z); pk[7] = f2bf(f1.w);
            } else {
#pragma unroll
                for (int e = 0; e < 8; ++e) pk[e] = 0;
            }
            *(ushort8*)(Wb + (size_t)n * KPAD + g * 8) = pk;
        }
    }
}

// ---------------------------------------------------------------------------
// Scan pass B (verified): grid (NCHUNK, nb). Block (chunk,b) loads the
// chunk's start state from ckpt, runs <=16 steps, writes sig rows (bf16).
// ---------------------------------------------------------------------------
__global__ __launch_bounds__(512) void sig_write_kernel(const float* __restrict__ inp,
                                                        const float* __restrict__ ckpt,
                                                        unsigned short* __restrict__ sig) {
    __shared__ float sDx[CH * CC];

    const int chunk = blockIdx.x;
    const int b     = blockIdx.y;
    const int tid   = threadIdx.x;
    const int t0    = chunk * CH;
    const int t1    = (chunk == NCHUNK - 1) ? TSTEPS : t0 + CH;

    const float* ip = inp + (size_t)b * LSEQ * CIN;
    for (int i = tid; i < (t1 - t0) * CC; i += 512) {
        int t = t0 + (i >> 3), c = i & 7;
        sDx[i] = (c == 0) ? (1.0f / 255.0f)
                          : ip[(t + 1) * CIN + (c - 1)] - ip[t * CIN + (c - 1)];
    }
    __syncthreads();

    const int i1 = tid >> 6;
    const int i2 = (tid >> 3) & 7;
    const int i3 = tid & 7;

    float a1own, a2own, a3;
    float a4[8];
    if (chunk == 0) {
        a1own = a2own = a3 = 0.0f;
#pragma unroll
        for (int e = 0; e < 8; ++e) a4[e] = 0.0f;
    } else {
        const float* cp = ckpt + ((size_t)b * 15 + (chunk - 1)) * NSIG;
        a1own = cp[i1];
        a2own = cp[8 + (tid >> 3)];
        a3    = cp[72 + tid];
        float4 q0 = *(const float4*)&cp[584 + tid * 8];
        float4 q1 = *(const float4*)&cp[584 + tid * 8 + 4];
        a4[0] = q0.x; a4[1] = q0.y; a4[2] = q0.z; a4[3] = q0.w;
        a4[4] = q1.x; a4[5] = q1.y; a4[6] = q1.z; a4[7] = q1.w;
    }

    for (int t = t0; t < t1; ++t) {
        const float* v = &sDx[(t - t0) * CC];
        const float4 vlo = *(const float4*)&v[0];
        const float4 vhi = *(const float4*)&v[4];
        const float va = v[i1], vb = v[i2], vc = v[i3];
        const float e3s = va * vb * vc * (1.0f / 6.0f);
        const float T4 = e3s * 0.25f + a1own * vb * vc * (1.0f / 6.0f)
                       + a2own * vc * 0.5f + a3;
        a4[0] += vlo.x * T4; a4[1] += vlo.y * T4;
        a4[2] += vlo.z * T4; a4[3] += vlo.w * T4;
        a4[4] += vhi.x * T4; a4[5] += vhi.y * T4;
        a4[6] += vhi.z * T4; a4[7] += vhi.w * T4;
        a3 += e3s + (a1own * vb * 0.5f + a2own) * vc;
        a2own += vb * (0.5f * va + a1own);
        a1own += va;

        unsigned short* row = sig + ((size_t)b * TSTEPS + t) * KPAD;
        ushort8 pack;
#pragma unroll
        for (int e = 0; e < 8; ++e) pack[e] = f2bf(a4[e]);
        *(ushort8*)(row + 584 + tid * 8) = pack;                // level 4
        row[72 + tid] = f2bf(a3);                               // level 3
        if ((tid & 63) == 0) row[i1] = f2bf(a1own);             // level 1
        if ((tid & 7) == 0) row[8 + (tid >> 3)] = f2bf(a2own);  // level 2
        if (tid >= 448 && tid < 504) row[4232 + tid] = 0;       // pad
    }
}

// ---------------------------------------------------------------------------
// MFMA GEMM (R10-verified, best measured: 74.4us, MfmaUtil 45%, conflicts 0).
// BM=256 x BN=128, BK=64, 8 waves (4Mx2N, each 64x64), 3 LDS buffers.
// Cross-tile pipeline: every ds_read burst streams under an MFMA cluster;
// ONE barrier per K-tile placed BETWEEN the two MFMA clusters; counted
// vmcnt(6) keeps tile t+2's loads in flight across the barrier.
// T2 XOR-swizzle (linear LDS dest + pre-swizzled global src + matching XOR
// on ds_read), XCD-grouped block swizzle, T5 setprio around MFMA clusters.
// ---------------------------------------------------------------------------
__global__ __launch_bounds__(512) void gemm_kernel(const unsigned short* __restrict__ A,
                                                   const unsigned short* __restrict__ Wb,
                                                   const float* __restrict__ bias,
                                                   float* __restrict__ out,
                                                   int Mrows) {
    __shared__ unsigned short As[3][BM * 64];   // 3 x 32 KB
    __shared__ unsigned short Bs[3][BN * 64];   // 3 x 16 KB

    const int tid = threadIdx.x;
    int nt, mt;
    if (gridDim.y == 64) {                     // full dispatch (256 blocks)
        const int li = blockIdx.y * 4 + blockIdx.x;
        const int x  = li & 7;                 // XCD (round-robin assumption)
        const int j  = li >> 3;                // 0..31 within XCD
        mt = x * 8 + (j >> 2);                 // 8 m-panels per XCD
        nt = j & 3;
    } else {
        nt = blockIdx.x; mt = blockIdx.y;
    }
    const int lane = tid & 63;
    const int wv   = tid >> 6;                 // 0..7
    const int wr   = wv >> 1;                  // 0..3 (M)
    const int wc   = wv & 1;                   // 0..1 (N)
    const int lr   = lane & 15;
    const int lq   = lane >> 4;                // 0..3
    const int sb   = lr & 7;                   // read-side swizzle key

    const f32x4 z4 = {0.0f, 0.0f, 0.0f, 0.0f};
    f32x4 acc[4][4];
#pragma unroll
    for (int i = 0; i < 4; ++i)
#pragma unroll
        for (int j = 0; j < 4; ++j) acc[i][j] = z4;

    const int srow = tid >> 3;                          // 0..63
    const int gcb  = (tid & 7) ^ (srow & 7);            // pre-swizzled src blk
    const int scol = gcb * 8;

    const unsigned short* aptr[4];
    const unsigned short* bptr[2];
#pragma unroll
    for (int i = 0; i < 4; ++i) {
        int gr = mt * BM + i * 64 + srow;
        if (gr >= Mrows) gr = 0;
        aptr[i] = A + (size_t)gr * KPAD + scol;
    }
#pragma unroll
    for (int i = 0; i < 2; ++i)
        bptr[i] = Wb + (size_t)(nt * BN + i * 64 + srow) * KPAD + scol;

    const int kel0 = ((lq)     ^ sb) * 8;               // ks=0 swizzled col
    const int kel1 = ((4 + lq) ^ sb) * 8;               // ks=1 swizzled col
    const int aoff = (wr * 64 + lr) * 64;
    const int boff = (wc * 64 + lr) * 64;

#define STAGE_ALL(buf, koff)                                                \
    do {                                                                    \
        _Pragma("unroll")                                                   \
        for (int i_ = 0; i_ < 4; ++i_)                                      \
            GLDS16(aptr[i_] + (koff),                                       \
                   ((char*)As[buf]) + i_ * 8192 + tid * 16);                \
        _Pragma("unroll")                                                   \
        for (int i_ = 0; i_ < 2; ++i_)                                      \
            GLDS16(bptr[i_] + (koff),                                       \
                   ((char*)Bs[buf]) + i_ * 8192 + tid * 16);                \
    } while (0)

    // prologue: tiles 0 and 1 in flight; wait tile 0 (6 of tile 1 remain)
    STAGE_ALL(0, 0);
    STAGE_ALL(1, 64);
    asm volatile("s_waitcnt vmcnt(6)" ::: "memory");
    __builtin_amdgcn_sched_barrier(0);
    __builtin_amdgcn_s_barrier();
    __builtin_amdgcn_sched_barrier(0);

    // issue ph0 reads of tile 0
    bf16x8 afP[4], bfP[4], afN[4], bfN[4];
    {
        const unsigned short* as0 = &As[0][0];
        const unsigned short* bs0 = &Bs[0][0];
#pragma unroll
        for (int i = 0; i < 4; ++i)
            afP[i] = *(const bf16x8*)&as0[aoff + i * 1024 + kel0];
#pragma unroll
        for (int j = 0; j < 4; ++j)
            bfP[j] = *(const bf16x8*)&bs0[boff + j * 1024 + kel0];
    }
    __builtin_amdgcn_sched_barrier(0);

    int cur = 0, nxt = 1, nn = 2;
    for (int t = 0; t < NKT; ++t) {
        const unsigned short* as = &As[0][0] + cur * (BM * 64);
        const unsigned short* bs = &Bs[0][0] + cur * (BN * 64);

        // ---- issue ph1(t) reads (8) + 6 gloads for t+2 ----
#pragma unroll
        for (int i = 0; i < 4; ++i)
            afN[i] = *(const bf16x8*)&as[aoff + i * 1024 + kel1];
#pragma unroll
        for (int j = 0; j < 4; ++j)
            bfN[j] = *(const bf16x8*)&bs[boff + j * 1024 + kel1];
        if (t + 2 < NKT) STAGE_ALL(nn, (t + 2) * 64);
        __builtin_amdgcn_sched_barrier(0);

        // ---- ph0 MFMA (ph1 reads stream underneath) ----
        asm volatile("s_waitcnt lgkmcnt(8)" ::: "memory");
        __builtin_amdgcn_sched_barrier(0);
        __builtin_amdgcn_s_setprio(1);
#pragma unroll
        for (int i = 0; i < 4; ++i)
#pragma unroll
            for (int j = 0; j < 4; ++j)
                acc[i][j] = __builtin_amdgcn_mfma_f32_16x16x32_bf16(
                    afP[i], bfP[j], acc[i][j], 0, 0, 0);
        __builtin_amdgcn_s_setprio(0);
        __builtin_amdgcn_sched_barrier(0);

        // ---- all buf(t) reads done; cross into tile t+1's buffer ----
        asm volatile("s_waitcnt lgkmcnt(0)" ::: "memory");
        __builtin_amdgcn_sched_barrier(0);
        if (t + 1 < NKT) {
            if (t + 2 < NKT) {
                asm volatile("s_waitcnt vmcnt(6)" ::: "memory");
            } else {
                asm volatile("s_waitcnt vmcnt(0)" ::: "memory");
            }
            __builtin_amdgcn_sched_barrier(0);
            __builtin_amdgcn_s_barrier();
            __builtin_amdgcn_sched_barrier(0);
            // issue ph0 reads of tile t+1 (stream under ph1 MFMA below)
            const unsigned short* asn = &As[0][0] + nxt * (BM * 64);
            const unsigned short* bsn = &Bs[0][0] + nxt * (BN * 64);
#pragma unroll
            for (int i = 0; i < 4; ++i)
                afP[i] = *(const bf16x8*)&asn[aoff + i * 1024 + kel0];
#pragma unroll
            for (int j = 0; j < 4; ++j)
                bfP[j] = *(const bf16x8*)&bsn[boff + j * 1024 + kel0];
            __builtin_amdgcn_sched_barrier(0);
        }

        // ---- ph1 MFMA (tile t+1's ph0 reads stream underneath) ----
        __builtin_amdgcn_s_setprio(1);
#pragma unroll
        for (int i = 0; i < 4; ++i)
#pragma unroll
            for (int j = 0; j < 4; ++j)
                acc[i][j] = __builtin_amdgcn_mfma_f32_16x16x32_bf16(
                    afN[i], bfN[j], acc[i][j], 0, 0, 0);
        __builtin_amdgcn_s_setprio(0);
        __builtin_amdgcn_sched_barrier(0);

        const int tmp = cur; cur = nxt; nxt = nn; nn = tmp;
    }

    float bn[4];
#pragma unroll
    for (int j = 0; j < 4; ++j)
        bn[j] = bias[nt * BN + wc * 64 + j * 16 + lr];

#pragma unroll
    for (int i = 0; i < 4; ++i) {
        const int mbase = mt * BM + wr * 64 + i * 16 + lq * 4;
#pragma unroll
        for (int r = 0; r < 4; ++r) {
            const int m = mbase + r;
            if (m < Mrows) {
#pragma unroll
                for (int j = 0; j < 4; ++j) {
                    const int n = nt * BN + wc * 64 + j * 16 + lr;
                    out[(size_t)m * ODIM + n] = acc[i][j][r] + bn[j];
                }
            }
        }
    }
#undef STAGE_ALL
}

extern "C" void kernel_launch(void* const* d_in, const int* in_sizes, int n_in,
                              void* d_out, int out_size, void* d_ws, size_t ws_size,
                              hipStream_t stream) {
    const float* inp  = (const float*)d_in[0];
    const float* W    = (const float*)d_in[1];
    const float* bias = (const float*)d_in[2];
    float* out = (float*)d_out;

    const size_t wbBytes = (size_t)ODIM * KPAD * sizeof(unsigned short);
    const size_t sigPB   = (size_t)TSTEPS * KPAD * sizeof(unsigned short); // 2.42 MB
    const size_t ckptPB  = (size_t)15 * NSIG * sizeof(float);              // 0.28 MB
    const size_t perB    = sigPB + ckptPB;

    int nbMax = (int)((ws_size - wbBytes) / perB);
    if (nbMax > BATCH) nbMax = BATCH;
    if (nbMax < 1) nbMax = 1;

    unsigned short* sig  = (unsigned short*)d_ws;
    float*          ckpt = (float*)((char*)d_ws + (size_t)nbMax * sigPB);
    unsigned short* Wb   = (unsigned short*)((char*)d_ws + (ws_size - wbBytes));

    for (int b0 = 0; b0 < BATCH; b0 += nbMax) {
        const int nb = (b0 + nbMax <= BATCH) ? nbMax : (BATCH - b0);
        const int Mrows = nb * TSTEPS;
        const float* ipb = inp + (size_t)b0 * LSEQ * CIN;
        prep_kernel<<<4 * nb + WCVT_BLK, 512, 0, stream>>>(ipb, ckpt, W, Wb, nb);
        sig_write_kernel<<<dim3(NCHUNK, nb), 512, 0, stream>>>(ipb, ckpt, sig);
        gemm_kernel<<<dim3(ODIM / BN, (Mrows + BM - 1) / BM), 512, 0, stream>>>(
            sig, Wb, bias, out + (size_t)b0 * TSTEPS * ODIM, Mrows);
    }
}